// Round 3
// baseline (665.162 us; speedup 1.0000x reference)
//
#include <hip/hip_runtime.h>
#include <stdint.h>

// ---------------------------------------------------------------------------
// Fused MHA block: B=4, L=1024, D=1024, H=16, DK=DV=64.
// bf16 MFMA (16x16x32) everywhere; fp32 accumulate.
// Verified gfx950 layouts:
//   A-frag : A[m=lane&15][k=quad*8+j]        (16B contiguous)
//   B-frag : B[k=quad*8+j][n=lane&15]  == BT[n][k] contiguous -> use BT inputs
//   C/D    : col=lane&15, row=quad*4+reg
// ---------------------------------------------------------------------------

typedef __bf16 bf16;
typedef __attribute__((ext_vector_type(4))) float f32x4;
typedef __attribute__((ext_vector_type(8))) bf16  bf16x8;
typedef __attribute__((ext_vector_type(4))) bf16  bf16x4;

#define MFMA16(a, b, c) __builtin_amdgcn_mfma_f32_16x16x32_bf16((a), (b), (c), 0, 0, 0)

__device__ __forceinline__ void g2lds16(const void* g, void* l) {
  __builtin_amdgcn_global_load_lds(
      (const __attribute__((address_space(1))) uint32_t*)g,
      (__attribute__((address_space(3))) uint32_t*)l, 16, 0, 0);
}

// ---------------------------------------------------------------------------
// cast fp32 -> bf16, 4 elems/thread, z selects tensor
// ---------------------------------------------------------------------------
__global__ __launch_bounds__(256) void cast3_kernel(
    const float* __restrict__ q, const float* __restrict__ k, const float* __restrict__ v,
    bf16* __restrict__ qb, bf16* __restrict__ kb, bf16* __restrict__ vb)
{
  const int z = blockIdx.y;
  const float* src = (z == 0) ? q : (z == 1) ? k : v;
  bf16* dst = (z == 0) ? qb : (z == 1) ? kb : vb;
  const int idx = blockIdx.x * 256 + threadIdx.x;       // 0..2^20-1
  float4 f = ((const float4*)src)[idx];
  bf16x4 o = { (bf16)f.x, (bf16)f.y, (bf16)f.z, (bf16)f.w };
  ((bf16x4*)dst)[idx] = o;
}

// ---------------------------------------------------------------------------
// transpose+cast weights [1024x1024] fp32 -> BT bf16 (o[n][k] = w[k][n])
// ---------------------------------------------------------------------------
__global__ __launch_bounds__(256) void transpose_w_kernel(
    const float* __restrict__ w0, const float* __restrict__ w1,
    const float* __restrict__ w2, const float* __restrict__ w3,
    bf16* __restrict__ o0, bf16* __restrict__ o1, bf16* __restrict__ o2, bf16* __restrict__ o3)
{
  const int z = blockIdx.z;
  const float* w = (z == 0) ? w0 : (z == 1) ? w1 : (z == 2) ? w2 : w3;
  bf16* o = (z == 0) ? o0 : (z == 1) ? o1 : (z == 2) ? o2 : o3;
  __shared__ bf16 tile[32][33];
  const int n0 = blockIdx.x * 32, k0 = blockIdx.y * 32;
  const int tx = threadIdx.x, ty = threadIdx.y;         // (32,8)
  for (int j = 0; j < 4; ++j)
    tile[ty * 4 + j][tx] = (bf16)w[(size_t)(k0 + ty * 4 + j) * 1024 + n0 + tx];
  __syncthreads();
  for (int j = 0; j < 4; ++j)
    o[(size_t)(n0 + ty * 4 + j) * 1024 + k0 + tx] = tile[tx][ty * 4 + j];
}

// ---------------------------------------------------------------------------
// transpose per-head V: vhT[bh][d][l] = vh[b*1024+l][h*64+d]
// ---------------------------------------------------------------------------
__global__ __launch_bounds__(256) void transpose_vh_kernel(
    const bf16* __restrict__ vh, bf16* __restrict__ vhT)
{
  const int bh = blockIdx.z;
  const int b = bh >> 4, h = bh & 15;
  __shared__ bf16 tile[32][33];
  const int d0 = blockIdx.x * 32, l0 = blockIdx.y * 32;
  const int tx = threadIdx.x, ty = threadIdx.y;         // (32,8)
  for (int j = 0; j < 4; ++j)
    tile[ty * 4 + j][tx] = vh[(size_t)(b * 1024 + l0 + ty * 4 + j) * 1024 + h * 64 + d0 + tx];
  __syncthreads();
  for (int j = 0; j < 4; ++j)
    vhT[((size_t)bh * 64 + d0 + ty * 4 + j) * 1024 + l0 + tx] = tile[tx][ty * 4 + j];
}

// ---------------------------------------------------------------------------
// 128x128-tile bf16 GEMM: C[M=4096,N=1024] = A[4096,1024] @ BT^T + bias
// BK=32, 4 waves (2x2 of 64x64), global_load_lds width-16 staging (m97 shape)
// ---------------------------------------------------------------------------
template <typename OutT>
__device__ __forceinline__ void gemm128_body(
    const bf16* __restrict__ A, const bf16* __restrict__ BT,
    const float* __restrict__ bias, OutT* __restrict__ C)
{
  __shared__ __align__(16) bf16 As[128 * 32];
  __shared__ __align__(16) bf16 Bs[128 * 32];
  const int t = threadIdx.x;
  const int lane = t & 63, w = t >> 6;
  const int quad = lane >> 4, l16 = lane & 15;
  const int m0 = blockIdx.y * 128, n0 = blockIdx.x * 128;
  const int wm = w >> 1, wn = w & 1;
  const int srow = t >> 2, scol = (t & 3) * 8;          // 16B chunks, lane-linear LDS

  f32x4 acc[4][4];
  for (int mt = 0; mt < 4; ++mt)
    for (int nt = 0; nt < 4; ++nt)
      acc[mt][nt] = (f32x4){0.f, 0.f, 0.f, 0.f};

  for (int kb = 0; kb < 32; ++kb) {
    const int k0 = kb * 32;
    for (int i = 0; i < 2; ++i) {
      const int r = srow + i * 64;
      g2lds16(A  + (size_t)(m0 + r) * 1024 + k0 + scol, As + r * 32 + scol);
      g2lds16(BT + (size_t)(n0 + r) * 1024 + k0 + scol, Bs + r * 32 + scol);
    }
    __syncthreads();
    bf16x8 af[4], bfr[4];
    for (int mt = 0; mt < 4; ++mt)
      af[mt] = *(const bf16x8*)(As + (wm * 64 + mt * 16 + l16) * 32 + quad * 8);
    for (int nt = 0; nt < 4; ++nt)
      bfr[nt] = *(const bf16x8*)(Bs + (wn * 64 + nt * 16 + l16) * 32 + quad * 8);
    for (int mt = 0; mt < 4; ++mt)
      for (int nt = 0; nt < 4; ++nt)
        acc[mt][nt] = MFMA16(af[mt], bfr[nt], acc[mt][nt]);
    __syncthreads();
  }

  for (int mt = 0; mt < 4; ++mt)
    for (int nt = 0; nt < 4; ++nt)
      for (int r = 0; r < 4; ++r) {
        const int rr = m0 + wm * 64 + mt * 16 + quad * 4 + r;
        const int cc = n0 + wn * 64 + nt * 16 + l16;
        C[(size_t)rr * 1024 + cc] = (OutT)(acc[mt][nt][r] + bias[cc]);
      }
}

__global__ __launch_bounds__(256) void gemm_qkv_kernel(
    const bf16* qb, const bf16* kb, const bf16* vb,
    const bf16* wqT, const bf16* wkT, const bf16* wvT,
    const float* bq, const float* bk, const float* bv,
    bf16* qh, bf16* kh, bf16* vh)
{
  const int z = blockIdx.z;
  const bf16* A   = (z == 0) ? qb  : (z == 1) ? kb  : vb;
  const bf16* BT  = (z == 0) ? wqT : (z == 1) ? wkT : wvT;
  const float* bi = (z == 0) ? bq  : (z == 1) ? bk  : bv;
  bf16* C         = (z == 0) ? qh  : (z == 1) ? kh  : vh;
  gemm128_body<bf16>(A, BT, bi, C);
}

__global__ __launch_bounds__(256) void gemm_fc_kernel(
    const bf16* A, const bf16* BT, const float* bias, float* C)
{
  gemm128_body<float>(A, BT, bias, C);
}

// ---------------------------------------------------------------------------
// attention v5: v4 (kt-split + XCD swizzle) + full-line NT attn stores.
// Round-2 counters: WRITE_SIZE 619 MB vs ~270 MB ideal. Cause: each NT store
// instruction wrote 16B of every 32B (lane stride 32B, two instructions
// filling alternate halves) -> partial-line HBM writes, ~2x amplification on
// the 256 MB attn stream. Fix: one instruction = 64 lanes x 16B contiguous
// (1024B, full 64B lines). Also: pass-2 walks kt in reverse (LIFO L2 reuse
// of pass-1's K tiles; per-XCD working set is borderline ~4.2 MB vs 4 MB L2).
// ---------------------------------------------------------------------------
__global__ __launch_bounds__(256, 8) void attn_kernel(
    const bf16* __restrict__ qh, const bf16* __restrict__ kh,
    const bf16* __restrict__ vhT, const uint8_t* __restrict__ mask,
    float* __restrict__ attn_out, bf16* __restrict__ outh)
{
  // XCD swizzle: physical g -> logical lb so each XCD owns an 8-head slice.
  const int g  = blockIdx.x;                 // 0..2047
  const int lb = (g & 7) * 256 + (g >> 3);   // bijective (2048 % 8 == 0)
  const int bh = lb >> 5;                    // b*16 + h
  const int qt = lb & 31;                    // 0..31 (32-row Q tile)
  const int b = bh >> 4, h = bh & 15;
  const int t = threadIdx.x, w = t >> 6, lane = t & 63;
  const int quad = lane >> 4, l16 = lane & 15;
  const int h2 = w & 1;                      // column (kt) half: kt in [h2*4, h2*4+4)
  const int rh = w >> 1;                     // row half
  const int qrow0 = qt * 32 + rh * 16;
  const int kt0 = h2 * 4;

  // P tiles (per wave 16x136 bf16) -- reused as O-merge buffer at the end
  __shared__ __align__(16) char shmem[4 * 16 * 136 * 2];   // 17408 B
  bf16  (*Pl)[16][136] = (bf16 (*)[16][136])shmem;
  float (*Obuf)[16][68] = (float (*)[16][68])shmem;        // 8704 B, overlays Pl
  __shared__ float stats[2][2][16][2];       // [rh][h2][row16][{m,l}]

  const bf16* qbase = qh + (size_t)b * (1024 * 1024) + h * 64;
  const bf16* kbase = kh + (size_t)b * (1024 * 1024) + h * 64;
  const bf16* vbase = vhT + (size_t)bh * (64 * 1024);
  const uint8_t* mbase = mask + (size_t)b * (1024 * 1024);

  // ---- wave-uniform mask probe: this wave's 16 rows x its 512 cols --------
  uint32_t macc = 0;
  {
    const uint4* mp = (const uint4*)(mbase +
        (size_t)(qrow0 + (lane >> 2)) * 1024 + h2 * 512 + (lane & 3) * 128);
    for (int i = 0; i < 8; ++i) {
      uint4 mv = mp[i];
      macc |= mv.x | mv.y | mv.z | mv.w;
    }
  }
  const bool has_mask = __any(macc != 0);

  bf16x8 Qf0 = *(const bf16x8*)(qbase + (size_t)(qrow0 + l16) * 1024 + quad * 8);
  bf16x8 Qf1 = *(const bf16x8*)(qbase + (size_t)(qrow0 + l16) * 1024 + 32 + quad * 8);

  const float scale2 = 0.125f * 1.44269504f;   // 1/sqrt(64) * log2(e)
  float m[4], l[4];
  for (int r = 0; r < 4; ++r) { m[r] = -3e38f; l[r] = 0.f; }

  // ---- pass 1: online max / sum-exp2 over this wave's 4 kt tiles ----------
  for (int kt = kt0; kt < kt0 + 4; ++kt) {
#pragma unroll
    for (int nt = 0; nt < 8; ++nt) {
      const int colb = kt * 128 + nt * 16;
      const bf16* kp = kbase + (size_t)(colb + l16) * 1024 + quad * 8;
      bf16x8 Bf0 = *(const bf16x8*)(kp);
      bf16x8 Bf1 = *(const bf16x8*)(kp + 32);
      f32x4 s = (f32x4){0.f, 0.f, 0.f, 0.f};
      s = MFMA16(Qf0, Bf0, s);
      s = MFMA16(Qf1, Bf1, s);
      s = s * scale2;
      if (has_mask) {
        const int col = colb + l16;
        for (int r = 0; r < 4; ++r)
          if (mbase[(size_t)(qrow0 + quad * 4 + r) * 1024 + col]) s[r] = -1e9f;
      }
#pragma unroll
      for (int r = 0; r < 4; ++r) {
        const float nm = fmaxf(m[r], s[r]);
        l[r] = l[r] * __builtin_amdgcn_exp2f(m[r] - nm) + __builtin_amdgcn_exp2f(s[r] - nm);
        m[r] = nm;
      }
    }
  }
  // merge across the 16 lanes (l16) holding one row
#pragma unroll
  for (int r = 0; r < 4; ++r) {
    float mm = m[r], ll = l[r];
    for (int xm = 1; xm < 16; xm <<= 1) {
      float om = __shfl_xor(mm, xm);
      float ol = __shfl_xor(ll, xm);
      float nm = fmaxf(mm, om);
      ll = ll * __builtin_amdgcn_exp2f(mm - nm) + ol * __builtin_amdgcn_exp2f(om - nm);
      mm = nm;
    }
    m[r] = mm;
    l[r] = ll;
  }
  // cross-wave merge with the partner kt-half via LDS stats
  if (l16 == 0) {
#pragma unroll
    for (int r = 0; r < 4; ++r) {
      stats[rh][h2][quad * 4 + r][0] = m[r];
      stats[rh][h2][quad * 4 + r][1] = l[r];
    }
  }
  __syncthreads();
#pragma unroll
  for (int r = 0; r < 4; ++r) {
    const float om = stats[rh][h2 ^ 1][quad * 4 + r][0];
    const float ol = stats[rh][h2 ^ 1][quad * 4 + r][1];
    const float nm = fmaxf(m[r], om);
    const float nl = l[r] * __builtin_amdgcn_exp2f(m[r] - nm) +
                     ol   * __builtin_amdgcn_exp2f(om - nm);
    m[r] = nm;
    l[r] = 1.0f / nl;                          // store inverse denom
  }

  // ---- pass 2: recompute S, write attn (full-line NT), partial P@V --------
  f32x4 O[4];
  for (int c = 0; c < 4; ++c) O[c] = (f32x4){0.f, 0.f, 0.f, 0.f};

  float* abase = attn_out + (size_t)(h * 4 + b) * (1024 * 1024);  // (h*B + b)
  bf16 (*Pw)[136] = Pl[w];

  for (int kt = kt0 + 3; kt >= kt0; --kt) {    // reverse: LIFO L2 reuse
#pragma unroll
    for (int nt = 0; nt < 8; ++nt) {
      const int colb = kt * 128 + nt * 16;
      const bf16* kp = kbase + (size_t)(colb + l16) * 1024 + quad * 8;
      bf16x8 Bf0 = *(const bf16x8*)(kp);
      bf16x8 Bf1 = *(const bf16x8*)(kp + 32);
      f32x4 s = (f32x4){0.f, 0.f, 0.f, 0.f};
      s = MFMA16(Qf0, Bf0, s);
      s = MFMA16(Qf1, Bf1, s);
      s = s * scale2;
      if (has_mask) {
        const int col = colb + l16;
        for (int r = 0; r < 4; ++r)
          if (mbase[(size_t)(qrow0 + quad * 4 + r) * 1024 + col]) s[r] = -1e9f;
      }
#pragma unroll
      for (int r = 0; r < 4; ++r) {
        float p = __builtin_amdgcn_exp2f(s[r] - m[r]) * l[r];
        Pw[quad * 4 + r][nt * 16 + l16] = (bf16)p;
      }
    }
    // full-line NT attn store: each instruction = 64 lanes x 16B = 1024B
    // contiguous (lanes 0-31 row 2j, lanes 32-63 row 2j+1; 512B per row seg).
#pragma unroll
    for (int j = 0; j < 8; ++j) {
      const int rr = j * 2 + (lane >> 5);
      const int cf = (lane & 31) * 4;
      bf16x4 pv = *(const bf16x4*)&Pw[rr][cf];
      f32x4 f0 = { (float)pv[0], (float)pv[1], (float)pv[2], (float)pv[3] };
      __builtin_nontemporal_store(f0,
          (f32x4*)(abase + (size_t)(qrow0 + rr) * 1024 + kt * 128 + cf));
    }
    // partial P @ V over this kt tile
#pragma unroll
    for (int kq = 0; kq < 4; ++kq) {
      bf16x8 Pf = *(const bf16x8*)&Pw[l16][kq * 32 + quad * 8];
#pragma unroll
      for (int nt2 = 0; nt2 < 4; ++nt2) {
        bf16x8 Vf = *(const bf16x8*)(vbase +
            (size_t)(nt2 * 16 + l16) * 1024 + kt * 128 + kq * 32 + quad * 8);
        O[nt2] = MFMA16(Pf, Vf, O[nt2]);
      }
    }
  }

  // ---- O merge across the two kt-halves (reuse P LDS) ---------------------
  __syncthreads();                             // all P tiles dead now
  if (h2 == 1) {
#pragma unroll
    for (int nt2 = 0; nt2 < 4; ++nt2)
      for (int r = 0; r < 4; ++r)
        Obuf[rh][quad * 4 + r][nt2 * 16 + l16] = O[nt2][r];
  }
  __syncthreads();
  if (h2 == 0) {
#pragma unroll
    for (int nt2 = 0; nt2 < 4; ++nt2)
      for (int r = 0; r < 4; ++r) {
        const float o = O[nt2][r] + Obuf[rh][quad * 4 + r][nt2 * 16 + l16];
        const int row = qrow0 + quad * 4 + r;
        const int col = h * 64 + nt2 * 16 + l16;
        outh[(size_t)(b * 1024 + row) * 1024 + col] = (bf16)o;
      }
  }
}

// ---------------------------------------------------------------------------
// residual + LayerNorm: one row (1024) per block
// ---------------------------------------------------------------------------
__global__ __launch_bounds__(256) void ln_kernel(
    const float* __restrict__ fc, const float* __restrict__ qres,
    const float* __restrict__ gamma, const float* __restrict__ beta,
    float* __restrict__ y)
{
  const int row = blockIdx.x;
  const int t = threadIdx.x;
  const size_t base = (size_t)row * 1024;
  float4 a  = *(const float4*)(fc + base + t * 4);
  float4 qv = *(const float4*)(qres + base + t * 4);
  float x0 = a.x + qv.x, x1 = a.y + qv.y, x2 = a.z + qv.z, x3 = a.w + qv.w;
  float s  = x0 + x1 + x2 + x3;
  float ss = x0 * x0 + x1 * x1 + x2 * x2 + x3 * x3;
  for (int xm = 1; xm < 64; xm <<= 1) {
    s  += __shfl_xor(s, xm);
    ss += __shfl_xor(ss, xm);
  }
  __shared__ float red[8];
  const int w = t >> 6, lane = t & 63;
  if (lane == 0) { red[w] = s; red[4 + w] = ss; }
  __syncthreads();
  s  = red[0] + red[1] + red[2] + red[3];
  ss = red[4] + red[5] + red[6] + red[7];
  const float mu = s * (1.f / 1024.f);
  const float var = ss * (1.f / 1024.f) - mu * mu;
  const float rstd = rsqrtf(var + 1e-5f);
  float4 g  = *(const float4*)(gamma + t * 4);
  float4 be = *(const float4*)(beta + t * 4);
  float4 o;
  o.x = (x0 - mu) * rstd * g.x + be.x;
  o.y = (x1 - mu) * rstd * g.y + be.y;
  o.z = (x2 - mu) * rstd * g.z + be.z;
  o.w = (x3 - mu) * rstd * g.w + be.w;
  *(float4*)(y + base + t * 4) = o;
}

// ---------------------------------------------------------------------------
extern "C" void kernel_launch(void* const* d_in, const int* in_sizes, int n_in,
                              void* d_out, int out_size, void* d_ws, size_t ws_size,
                              hipStream_t stream)
{
  const float*   q     = (const float*)d_in[0];
  const float*   k     = (const float*)d_in[1];
  const float*   v     = (const float*)d_in[2];
  const uint8_t* mask  = (const uint8_t*)d_in[3];
  const float*   wq    = (const float*)d_in[4];
  const float*   bq    = (const float*)d_in[5];
  const float*   wk    = (const float*)d_in[6];
  const float*   bk    = (const float*)d_in[7];
  const float*   wv    = (const float*)d_in[8];
  const float*   bv    = (const float*)d_in[9];
  const float*   wfc   = (const float*)d_in[10];
  const float*   bfc   = (const float*)d_in[11];
  const float*   gamma = (const float*)d_in[12];
  const float*   beta  = (const float*)d_in[13];

  float* y        = (float*)d_out;
  float* attn_out = (float*)d_out + (size_t)4 * 1024 * 1024;

  char* ws = (char*)d_ws;
  const size_t MB = (size_t)1 << 20;
  // live-range-packed: total 64 MB
  bf16* qb   = (bf16*)(ws + 0);        // dead after gemm_qkv
  bf16* kb   = (bf16*)(ws + 8 * MB);   // dead after gemm_qkv
  bf16* vb   = (bf16*)(ws + 16 * MB);  // dead after gemm_qkv
  bf16* wqT  = (bf16*)(ws + 24 * MB);
  bf16* wkT  = (bf16*)(ws + 26 * MB);
  bf16* wvT  = (bf16*)(ws + 28 * MB);
  bf16* wfcT = (bf16*)(ws + 30 * MB);
  bf16* qh   = (bf16*)(ws + 32 * MB);
  bf16* kh   = (bf16*)(ws + 40 * MB);
  bf16* vh   = (bf16*)(ws + 48 * MB);
  bf16* vhT  = (bf16*)(ws + 56 * MB);
  bf16* outh = (bf16*)(ws + 16 * MB);  // aliases vb (dead by then)
  float* fc  = (float*)(ws + 0);       // aliases qb+kb (dead by then)

  cast3_kernel<<<dim3(4096, 3), 256, 0, stream>>>(q, k, v, qb, kb, vb);
  transpose_w_kernel<<<dim3(32, 32, 4), dim3(32, 8), 0, stream>>>(
      wq, wk, wv, wfc, wqT, wkT, wvT, wfcT);
  gemm_qkv_kernel<<<dim3(8, 32, 3), 256, 0, stream>>>(
      qb, kb, vb, wqT, wkT, wvT, bq, bk, bv, qh, kh, vh);
  transpose_vh_kernel<<<dim3(2, 32, 64), dim3(32, 8), 0, stream>>>(vh, vhT);
  attn_kernel<<<dim3(2048), 256, 0, stream>>>(qh, kh, vhT, mask, attn_out, outh);
  gemm_fc_kernel<<<dim3(8, 32), 256, 0, stream>>>(outh, wfcT, bfc, fc);
  ln_kernel<<<4096, 256, 0, stream>>>(fc, q, gamma, beta, y);
}

// Round 4
// 470.642 us; speedup vs baseline: 1.4133x; 1.4133x over previous
//
#include <hip/hip_runtime.h>
#include <stdint.h>

// ---------------------------------------------------------------------------
// Fused MHA block: B=4, L=1024, D=1024, H=16, DK=DV=64.
// bf16 MFMA (16x16x32) everywhere; fp32 accumulate.
// Verified gfx950 layouts:
//   A-frag : A[m=lane&15][k=quad*8+j]        (16B contiguous)
//   B-frag : B[k=quad*8+j][n=lane&15]  == BT[n][k] contiguous -> use BT inputs
//   C/D    : col=lane&15, row=quad*4+reg
// ---------------------------------------------------------------------------

typedef __bf16 bf16;
typedef __attribute__((ext_vector_type(4))) float f32x4;
typedef __attribute__((ext_vector_type(8))) bf16  bf16x8;
typedef __attribute__((ext_vector_type(4))) bf16  bf16x4;

#define MFMA16(a, b, c) __builtin_amdgcn_mfma_f32_16x16x32_bf16((a), (b), (c), 0, 0, 0)

__device__ __forceinline__ void g2lds16(const void* g, void* l) {
  __builtin_amdgcn_global_load_lds(
      (const __attribute__((address_space(1))) uint32_t*)g,
      (__attribute__((address_space(3))) uint32_t*)l, 16, 0, 0);
}

// ---------------------------------------------------------------------------
// cast fp32 -> bf16, 4 elems/thread, z selects tensor
// ---------------------------------------------------------------------------
__global__ __launch_bounds__(256) void cast3_kernel(
    const float* __restrict__ q, const float* __restrict__ k, const float* __restrict__ v,
    bf16* __restrict__ qb, bf16* __restrict__ kb, bf16* __restrict__ vb)
{
  const int z = blockIdx.y;
  const float* src = (z == 0) ? q : (z == 1) ? k : v;
  bf16* dst = (z == 0) ? qb : (z == 1) ? kb : vb;
  const int idx = blockIdx.x * 256 + threadIdx.x;       // 0..2^20-1
  float4 f = ((const float4*)src)[idx];
  bf16x4 o = { (bf16)f.x, (bf16)f.y, (bf16)f.z, (bf16)f.w };
  ((bf16x4*)dst)[idx] = o;
}

// ---------------------------------------------------------------------------
// transpose+cast weights [1024x1024] fp32 -> BT bf16 (o[n][k] = w[k][n])
// ---------------------------------------------------------------------------
__global__ __launch_bounds__(256) void transpose_w_kernel(
    const float* __restrict__ w0, const float* __restrict__ w1,
    const float* __restrict__ w2, const float* __restrict__ w3,
    bf16* __restrict__ o0, bf16* __restrict__ o1, bf16* __restrict__ o2, bf16* __restrict__ o3)
{
  const int z = blockIdx.z;
  const float* w = (z == 0) ? w0 : (z == 1) ? w1 : (z == 2) ? w2 : w3;
  bf16* o = (z == 0) ? o0 : (z == 1) ? o1 : (z == 2) ? o2 : o3;
  __shared__ bf16 tile[32][33];
  const int n0 = blockIdx.x * 32, k0 = blockIdx.y * 32;
  const int tx = threadIdx.x, ty = threadIdx.y;         // (32,8)
  for (int j = 0; j < 4; ++j)
    tile[ty * 4 + j][tx] = (bf16)w[(size_t)(k0 + ty * 4 + j) * 1024 + n0 + tx];
  __syncthreads();
  for (int j = 0; j < 4; ++j)
    o[(size_t)(n0 + ty * 4 + j) * 1024 + k0 + tx] = tile[tx][ty * 4 + j];
}

// ---------------------------------------------------------------------------
// transpose per-head V: vhT[bh][d][l] = vh[b*1024+l][h*64+d]
// ---------------------------------------------------------------------------
__global__ __launch_bounds__(256) void transpose_vh_kernel(
    const bf16* __restrict__ vh, bf16* __restrict__ vhT)
{
  const int bh = blockIdx.z;
  const int b = bh >> 4, h = bh & 15;
  __shared__ bf16 tile[32][33];
  const int d0 = blockIdx.x * 32, l0 = blockIdx.y * 32;
  const int tx = threadIdx.x, ty = threadIdx.y;         // (32,8)
  for (int j = 0; j < 4; ++j)
    tile[ty * 4 + j][tx] = vh[(size_t)(b * 1024 + l0 + ty * 4 + j) * 1024 + h * 64 + d0 + tx];
  __syncthreads();
  for (int j = 0; j < 4; ++j)
    vhT[((size_t)bh * 64 + d0 + ty * 4 + j) * 1024 + l0 + tx] = tile[tx][ty * 4 + j];
}

// ---------------------------------------------------------------------------
// 128x128-tile bf16 GEMM: C[M=4096,N=1024] = A[4096,1024] @ BT^T + bias
// BK=32, 4 waves (2x2 of 64x64), global_load_lds width-16 staging (m97 shape)
// ---------------------------------------------------------------------------
template <typename OutT>
__device__ __forceinline__ void gemm128_body(
    const bf16* __restrict__ A, const bf16* __restrict__ BT,
    const float* __restrict__ bias, OutT* __restrict__ C)
{
  __shared__ __align__(16) bf16 As[128 * 32];
  __shared__ __align__(16) bf16 Bs[128 * 32];
  const int t = threadIdx.x;
  const int lane = t & 63, w = t >> 6;
  const int quad = lane >> 4, l16 = lane & 15;
  const int m0 = blockIdx.y * 128, n0 = blockIdx.x * 128;
  const int wm = w >> 1, wn = w & 1;
  const int srow = t >> 2, scol = (t & 3) * 8;          // 16B chunks, lane-linear LDS

  f32x4 acc[4][4];
  for (int mt = 0; mt < 4; ++mt)
    for (int nt = 0; nt < 4; ++nt)
      acc[mt][nt] = (f32x4){0.f, 0.f, 0.f, 0.f};

  for (int kb = 0; kb < 32; ++kb) {
    const int k0 = kb * 32;
    for (int i = 0; i < 2; ++i) {
      const int r = srow + i * 64;
      g2lds16(A  + (size_t)(m0 + r) * 1024 + k0 + scol, As + r * 32 + scol);
      g2lds16(BT + (size_t)(n0 + r) * 1024 + k0 + scol, Bs + r * 32 + scol);
    }
    __syncthreads();
    bf16x8 af[4], bfr[4];
    for (int mt = 0; mt < 4; ++mt)
      af[mt] = *(const bf16x8*)(As + (wm * 64 + mt * 16 + l16) * 32 + quad * 8);
    for (int nt = 0; nt < 4; ++nt)
      bfr[nt] = *(const bf16x8*)(Bs + (wn * 64 + nt * 16 + l16) * 32 + quad * 8);
    for (int mt = 0; mt < 4; ++mt)
      for (int nt = 0; nt < 4; ++nt)
        acc[mt][nt] = MFMA16(af[mt], bfr[nt], acc[mt][nt]);
    __syncthreads();
  }

  for (int mt = 0; mt < 4; ++mt)
    for (int nt = 0; nt < 4; ++nt)
      for (int r = 0; r < 4; ++r) {
        const int rr = m0 + wm * 64 + mt * 16 + quad * 4 + r;
        const int cc = n0 + wn * 64 + nt * 16 + l16;
        C[(size_t)rr * 1024 + cc] = (OutT)(acc[mt][nt][r] + bias[cc]);
      }
}

__global__ __launch_bounds__(256) void gemm_qkv_kernel(
    const bf16* qb, const bf16* kb, const bf16* vb,
    const bf16* wqT, const bf16* wkT, const bf16* wvT,
    const float* bq, const float* bk, const float* bv,
    bf16* qh, bf16* kh, bf16* vh)
{
  const int z = blockIdx.z;
  const bf16* A   = (z == 0) ? qb  : (z == 1) ? kb  : vb;
  const bf16* BT  = (z == 0) ? wqT : (z == 1) ? wkT : wvT;
  const float* bi = (z == 0) ? bq  : (z == 1) ? bk  : bv;
  bf16* C         = (z == 0) ? qh  : (z == 1) ? kh  : vh;
  gemm128_body<bf16>(A, BT, bi, C);
}

__global__ __launch_bounds__(256) void gemm_fc_kernel(
    const bf16* A, const bf16* BT, const float* bias, float* C)
{
  gemm128_body<float>(A, BT, bias, C);
}

// ---------------------------------------------------------------------------
// attention v6: structural K/V reuse via LDS staging.
// Round-3 counters: FETCH 298 MB (ideal ~30) -- L2 thrash from ~1 GB logical
// K reads (2 row-half waves x 2 passes straight from global) against a ~5 MB
// per-XCD working set. Fix: QBLK=128 blocks (8 waves x 16 rows, 512 thr),
// grid 512 = 64 bh x 8 qt (XCD swizzle). K tile (128x64) and V tile (64x128)
// staged in LDS via global_load_lds with XOR slot-swizzle (linear LDS dest,
// inverse-swizzled GLOBAL source; ds_read applies same XOR -> <=2-way banks).
// All 8 waves share each staged tile: logical K = 128 MB, V = 64 MB worst
// case; per-XCD L2 set ~3 MB (Q is pure streaming). No kt-split -> each wave
// owns complete rows: no stats/O merge. LDS 67.6 KB -> 2 blocks/CU.
// ---------------------------------------------------------------------------
__global__ __launch_bounds__(512, 4) void attn_kernel(
    const bf16* __restrict__ qh, const bf16* __restrict__ kh,
    const bf16* __restrict__ vhT, const uint8_t* __restrict__ mask,
    float* __restrict__ attn_out, bf16* __restrict__ outh)
{
  const int g  = blockIdx.x;                 // 0..511
  const int lb = (g & 7) * 64 + (g >> 3);    // bijective (512 % 8 == 0)
  const int bh = lb >> 3;                    // b*16 + h ; XCD c owns bh [8c,8c+8)
  const int qt = lb & 7;                     // 0..7 (128-row Q tile)
  const int b = bh >> 4, h = bh & 15;
  const int t = threadIdx.x, w = t >> 6, lane = t & 63;
  const int quad = lane >> 4, l16 = lane & 15;
  const int qrow0 = qt * 128 + w * 16;       // wave owns 16 complete rows

  __shared__ __align__(16) bf16 Ks[128 * 64];   // [krow][d]  16 KB, slot-swizzled
  __shared__ __align__(16) bf16 Vs[64 * 128];   // [d][krow]  16 KB, slot-swizzled
  __shared__ __align__(16) bf16 Pl[8][16][136]; // per-wave P  34.8 KB

  const bf16* qbase = qh + (size_t)b * (1024 * 1024) + h * 64;
  const bf16* kbase = kh + (size_t)b * (1024 * 1024) + h * 64;
  const bf16* vbase = vhT + (size_t)bh * (64 * 1024);
  const uint8_t* mbase = mask + (size_t)b * (1024 * 1024);

  // ---- wave-uniform mask probe: this wave's 16 rows x 1024 cols -----------
  uint32_t macc = 0;
  {
    const uint32_t* mrow = (const uint32_t*)(mbase +
        (size_t)(qrow0 + (lane >> 2)) * 1024 + (lane & 3) * 256);
    for (int i = 0; i < 16; ++i) {
      uint4 mv = *(const uint4*)(mrow + i * 4);
      macc |= mv.x | mv.y | mv.z | mv.w;
    }
  }
  const bool has_mask = __any(macc != 0);

  bf16x8 Qf0 = *(const bf16x8*)(qbase + (size_t)(qrow0 + l16) * 1024 + quad * 8);
  bf16x8 Qf1 = *(const bf16x8*)(qbase + (size_t)(qrow0 + l16) * 1024 + 32 + quad * 8);

  const float scale2 = 0.125f * 1.44269504f;   // 1/sqrt(64) * log2(e)
  float m[4], l[4];
  for (int r = 0; r < 4; ++r) { m[r] = -3e38f; l[r] = 0.f; }

  // ---- staging helpers (linear LDS dest, inverse-XOR global source) -------
  // K chunk c: LDS (row=c>>3, slot=c&7 of 16B) holds K[row][ (slot^(row&7))*8 ..+8 )
  // V chunk c: LDS (row=c>>4, slot=c&15) holds vhT[row][kt*128 + (slot^(row&7))*8 ..+8 )
#define STAGE_K(kt_)                                                          \
  for (int rd = 0; rd < 2; ++rd) {                                            \
    const int c = t + rd * 512;                                               \
    const int row = c >> 3, slot = c & 7;                                     \
    const int gs = slot ^ (row & 7);                                          \
    g2lds16(kbase + (size_t)((kt_) * 128 + row) * 1024 + gs * 8, Ks + c * 8); \
  }
#define STAGE_V(kt_)                                                          \
  for (int rd = 0; rd < 2; ++rd) {                                            \
    const int c = t + rd * 512;                                               \
    const int row = c >> 4, slot = c & 15;                                    \
    const int gs = slot ^ (row & 7);                                          \
    g2lds16(vbase + (size_t)row * 1024 + (kt_) * 128 + gs * 8, Vs + c * 8);   \
  }

  // ---- pass 1: online max / sum-exp2, K from LDS --------------------------
  for (int kt = 0; kt < 8; ++kt) {
    STAGE_K(kt);
    __syncthreads();
#pragma unroll
    for (int nt = 0; nt < 8; ++nt) {
      const int krow = nt * 16 + l16;
      const int rx = krow & 7;
      const bf16* kr = Ks + krow * 64;
      bf16x8 Bf0 = *(const bf16x8*)(kr + ((quad ^ rx) * 8));
      bf16x8 Bf1 = *(const bf16x8*)(kr + (((quad | 4) ^ rx) * 8));
      f32x4 s = (f32x4){0.f, 0.f, 0.f, 0.f};
      s = MFMA16(Qf0, Bf0, s);
      s = MFMA16(Qf1, Bf1, s);
      s = s * scale2;
      if (has_mask) {
        const int col = kt * 128 + nt * 16 + l16;
        for (int r = 0; r < 4; ++r)
          if (mbase[(size_t)(qrow0 + quad * 4 + r) * 1024 + col]) s[r] = -1e9f;
      }
#pragma unroll
      for (int r = 0; r < 4; ++r) {
        const float nm = fmaxf(m[r], s[r]);
        l[r] = l[r] * __builtin_amdgcn_exp2f(m[r] - nm) + __builtin_amdgcn_exp2f(s[r] - nm);
        m[r] = nm;
      }
    }
    __syncthreads();
  }
  // merge across the 16 lanes (l16) holding one row (wave owns full rows)
#pragma unroll
  for (int r = 0; r < 4; ++r) {
    float mm = m[r], ll = l[r];
    for (int xm = 1; xm < 16; xm <<= 1) {
      float om = __shfl_xor(mm, xm);
      float ol = __shfl_xor(ll, xm);
      float nm = fmaxf(mm, om);
      ll = ll * __builtin_amdgcn_exp2f(mm - nm) + ol * __builtin_amdgcn_exp2f(om - nm);
      mm = nm;
    }
    m[r] = mm;
    l[r] = 1.0f / ll;                          // store inverse denom
  }

  // ---- pass 2: recompute S, write attn (full-line NT), P@V from LDS -------
  f32x4 O[4];
  for (int c = 0; c < 4; ++c) O[c] = (f32x4){0.f, 0.f, 0.f, 0.f};

  float* abase = attn_out + (size_t)(h * 4 + b) * (1024 * 1024);  // (h*B + b)
  bf16 (*Pw)[136] = Pl[w];

  for (int kt = 0; kt < 8; ++kt) {
    STAGE_K(kt);
    STAGE_V(kt);
    __syncthreads();
#pragma unroll
    for (int nt = 0; nt < 8; ++nt) {
      const int krow = nt * 16 + l16;
      const int rx = krow & 7;
      const bf16* kr = Ks + krow * 64;
      bf16x8 Bf0 = *(const bf16x8*)(kr + ((quad ^ rx) * 8));
      bf16x8 Bf1 = *(const bf16x8*)(kr + (((quad | 4) ^ rx) * 8));
      f32x4 s = (f32x4){0.f, 0.f, 0.f, 0.f};
      s = MFMA16(Qf0, Bf0, s);
      s = MFMA16(Qf1, Bf1, s);
      s = s * scale2;
      if (has_mask) {
        const int col = kt * 128 + nt * 16 + l16;
        for (int r = 0; r < 4; ++r)
          if (mbase[(size_t)(qrow0 + quad * 4 + r) * 1024 + col]) s[r] = -1e9f;
      }
#pragma unroll
      for (int r = 0; r < 4; ++r) {
        float p = __builtin_amdgcn_exp2f(s[r] - m[r]) * l[r];
        Pw[quad * 4 + r][nt * 16 + l16] = (bf16)p;
      }
    }
    // full-line NT attn store: each instruction = 64 lanes x 16B = 1024B
    // contiguous (lanes 0-31 row 2j, lanes 32-63 row 2j+1; 512B per row seg).
#pragma unroll
    for (int j = 0; j < 8; ++j) {
      const int rr = j * 2 + (lane >> 5);
      const int cf = (lane & 31) * 4;
      bf16x4 pv = *(const bf16x4*)&Pw[rr][cf];
      f32x4 f0 = { (float)pv[0], (float)pv[1], (float)pv[2], (float)pv[3] };
      __builtin_nontemporal_store(f0,
          (f32x4*)(abase + (size_t)(qrow0 + rr) * 1024 + kt * 128 + cf));
    }
    // P @ V from LDS (slot-swizzled reads)
#pragma unroll
    for (int kq = 0; kq < 4; ++kq) {
      bf16x8 Pf = *(const bf16x8*)&Pw[l16][kq * 32 + quad * 8];
#pragma unroll
      for (int nt2 = 0; nt2 < 4; ++nt2) {
        const int vrow = nt2 * 16 + l16;
        const int gs = (kq * 4 + quad) ^ (vrow & 7);
        bf16x8 Vf = *(const bf16x8*)(Vs + vrow * 128 + gs * 8);
        O[nt2] = MFMA16(Pf, Vf, O[nt2]);
      }
    }
    __syncthreads();
  }

  // ---- output (wave owns complete rows; no merge) -------------------------
#pragma unroll
  for (int nt2 = 0; nt2 < 4; ++nt2)
    for (int r = 0; r < 4; ++r) {
      const int row = qrow0 + quad * 4 + r;
      const int col = h * 64 + nt2 * 16 + l16;
      outh[(size_t)(b * 1024 + row) * 1024 + col] = (bf16)O[nt2][r];
    }
#undef STAGE_K
#undef STAGE_V
}

// ---------------------------------------------------------------------------
// residual + LayerNorm: one row (1024) per block
// ---------------------------------------------------------------------------
__global__ __launch_bounds__(256) void ln_kernel(
    const float* __restrict__ fc, const float* __restrict__ qres,
    const float* __restrict__ gamma, const float* __restrict__ beta,
    float* __restrict__ y)
{
  const int row = blockIdx.x;
  const int t = threadIdx.x;
  const size_t base = (size_t)row * 1024;
  float4 a  = *(const float4*)(fc + base + t * 4);
  float4 qv = *(const float4*)(qres + base + t * 4);
  float x0 = a.x + qv.x, x1 = a.y + qv.y, x2 = a.z + qv.z, x3 = a.w + qv.w;
  float s  = x0 + x1 + x2 + x3;
  float ss = x0 * x0 + x1 * x1 + x2 * x2 + x3 * x3;
  for (int xm = 1; xm < 64; xm <<= 1) {
    s  += __shfl_xor(s, xm);
    ss += __shfl_xor(ss, xm);
  }
  __shared__ float red[8];
  const int w = t >> 6, lane = t & 63;
  if (lane == 0) { red[w] = s; red[4 + w] = ss; }
  __syncthreads();
  s  = red[0] + red[1] + red[2] + red[3];
  ss = red[4] + red[5] + red[6] + red[7];
  const float mu = s * (1.f / 1024.f);
  const float var = ss * (1.f / 1024.f) - mu * mu;
  const float rstd = rsqrtf(var + 1e-5f);
  float4 g  = *(const float4*)(gamma + t * 4);
  float4 be = *(const float4*)(beta + t * 4);
  float4 o;
  o.x = (x0 - mu) * rstd * g.x + be.x;
  o.y = (x1 - mu) * rstd * g.y + be.y;
  o.z = (x2 - mu) * rstd * g.z + be.z;
  o.w = (x3 - mu) * rstd * g.w + be.w;
  *(float4*)(y + base + t * 4) = o;
}

// ---------------------------------------------------------------------------
extern "C" void kernel_launch(void* const* d_in, const int* in_sizes, int n_in,
                              void* d_out, int out_size, void* d_ws, size_t ws_size,
                              hipStream_t stream)
{
  const float*   q     = (const float*)d_in[0];
  const float*   k     = (const float*)d_in[1];
  const float*   v     = (const float*)d_in[2];
  const uint8_t* mask  = (const uint8_t*)d_in[3];
  const float*   wq    = (const float*)d_in[4];
  const float*   bq    = (const float*)d_in[5];
  const float*   wk    = (const float*)d_in[6];
  const float*   bk    = (const float*)d_in[7];
  const float*   wv    = (const float*)d_in[8];
  const float*   bv    = (const float*)d_in[9];
  const float*   wfc   = (const float*)d_in[10];
  const float*   bfc   = (const float*)d_in[11];
  const float*   gamma = (const float*)d_in[12];
  const float*   beta  = (const float*)d_in[13];

  float* y        = (float*)d_out;
  float* attn_out = (float*)d_out + (size_t)4 * 1024 * 1024;

  char* ws = (char*)d_ws;
  const size_t MB = (size_t)1 << 20;
  // live-range-packed: total 64 MB
  bf16* qb   = (bf16*)(ws + 0);        // dead after gemm_qkv
  bf16* kb   = (bf16*)(ws + 8 * MB);   // dead after gemm_qkv
  bf16* vb   = (bf16*)(ws + 16 * MB);  // dead after gemm_qkv
  bf16* wqT  = (bf16*)(ws + 24 * MB);
  bf16* wkT  = (bf16*)(ws + 26 * MB);
  bf16* wvT  = (bf16*)(ws + 28 * MB);
  bf16* wfcT = (bf16*)(ws + 30 * MB);
  bf16* qh   = (bf16*)(ws + 32 * MB);
  bf16* kh   = (bf16*)(ws + 40 * MB);
  bf16* vh   = (bf16*)(ws + 48 * MB);
  bf16* vhT  = (bf16*)(ws + 56 * MB);
  bf16* outh = (bf16*)(ws + 16 * MB);  // aliases vb (dead by then)
  float* fc  = (float*)(ws + 0);       // aliases qb+kb (dead by then)

  cast3_kernel<<<dim3(4096, 3), 256, 0, stream>>>(q, k, v, qb, kb, vb);
  transpose_w_kernel<<<dim3(32, 32, 4), dim3(32, 8), 0, stream>>>(
      wq, wk, wv, wfc, wqT, wkT, wvT, wfcT);
  gemm_qkv_kernel<<<dim3(8, 32, 3), 256, 0, stream>>>(
      qb, kb, vb, wqT, wkT, wvT, bq, bk, bv, qh, kh, vh);
  transpose_vh_kernel<<<dim3(2, 32, 64), dim3(32, 8), 0, stream>>>(vh, vhT);
  attn_kernel<<<dim3(512), 512, 0, stream>>>(qh, kh, vhT, mask, attn_out, outh);
  gemm_fc_kernel<<<dim3(8, 32), 256, 0, stream>>>(outh, wfcT, bfc, fc);
  ln_kernel<<<4096, 256, 0, stream>>>(fc, q, gamma, beta, y);
}